// Round 1
// baseline (91.409 us; speedup 1.0000x reference)
//
#include <hip/hip_runtime.h>
#include <hip/hip_bf16.h>

#define B_N   1024
#define DIM_I 256
#define DIM_J 256
#define NUM_K 64

// ---------------------------------------------------------------------------
// Kernel 1: transpose + downconvert
//   Y [I][J][K] f32  ->  Y2 [I][K][J] bf16 (raw ushort)
// One block per (i, 64-wide j-tile). Reads and writes both fully coalesced.
// ---------------------------------------------------------------------------
__global__ __launch_bounds__(256) void kan_transpose(const float* __restrict__ Y,
                                                     unsigned short* __restrict__ Y2) {
    __shared__ float lds[64][65];  // +1 pad: conflict-free column reads
    const int i  = blockIdx.x >> 2;
    const int j0 = (blockIdx.x & 3) << 6;
    const float* src = Y + (size_t)(i * DIM_J + j0) * NUM_K;

    // read phase: 64 j x 64 k = one contiguous 16KB span
    for (int e = threadIdx.x; e < 4096; e += 256) {
        int jl = e >> 6, k = e & 63;
        lds[jl][k] = src[e];
    }
    __syncthreads();
    // write phase: consecutive lanes -> consecutive j (coalesced bf16 stores)
    for (int e = threadIdx.x; e < 4096; e += 256) {
        int kl = e >> 6, jl = e & 63;
        unsigned bits = __float_as_uint(lds[jl][kl]);
        // round-to-nearest-even bf16 (inputs are small finite values, no NaN/Inf)
        unsigned r = bits + 0x7FFFu + ((bits >> 16) & 1u);
        Y2[(size_t)(i * NUM_K + kl) * DIM_J + j0 + jl] = (unsigned short)(r >> 16);
    }
}

// ---------------------------------------------------------------------------
// Kernel 2: gather-lerp-reduce
//   out[b,j] = sum_i (1-t)*Y2[i,k0,j] + t*Y2[i,k0+1,j]
// One block per b. 128 threads, each owns j-pair (2*t, 2*t+1) -> dword loads.
// Per-i (offset, t) staged in LDS; inner-loop reads are wave-broadcast.
// ---------------------------------------------------------------------------
__global__ __launch_bounds__(128) void kan_main(const float* __restrict__ x,
                                                const float* __restrict__ Xg,
                                                const unsigned short* __restrict__ Y2,
                                                float* __restrict__ out) {
    __shared__ float Xs[NUM_K];
    __shared__ int   offs[DIM_I];
    __shared__ float ts[DIM_I];

    const int b = blockIdx.x;
    const int t = threadIdx.x;

    if (t < NUM_K) Xs[t] = Xg[t];
    __syncthreads();

    // phase 1: per-i interval index + lerp parameter
    for (int e = t; e < DIM_I; e += 128) {
        float xv = x[b * DIM_I + e];
        // uniform grid [-2,2], 64 pts: closed-form searchsorted + exact fixup
        int m = (int)floorf((xv + 2.0f) * (63.0f / 4.0f)) + 1;
        m = m < 1 ? 1 : (m > 63 ? 63 : m);
        while (m < 63 && Xs[m] <= xv) ++m;       // searchsorted(side="right")
        while (m > 1 && Xs[m - 1] > xv) --m;
        float x0 = Xs[m - 1], x1 = Xs[m];
        ts[e]   = (xv - x0) / (x1 - x0);
        offs[e] = (e * NUM_K + (m - 1)) * DIM_J;  // row k0 of Y2[i][.][.]
    }
    __syncthreads();

    const int jp = t << 1;
    float acc0 = 0.f, acc1 = 0.f;
    #pragma unroll 8
    for (int i = 0; i < DIM_I; ++i) {
        int   o  = offs[i];
        float tt = ts[i];
        // two adjacent bf16 j-values per dword; k0 row and k0+1 row (+DIM_J)
        unsigned pa = *reinterpret_cast<const unsigned*>(Y2 + o + jp);
        unsigned pb = *reinterpret_cast<const unsigned*>(Y2 + o + DIM_J + jp);
        float a0 = __uint_as_float(pa << 16);          // element jp   (low half)
        float a1 = __uint_as_float(pa & 0xFFFF0000u);  // element jp+1 (high half)
        float b0 = __uint_as_float(pb << 16);
        float b1 = __uint_as_float(pb & 0xFFFF0000u);
        acc0 += a0; acc0 = fmaf(tt, b0 - a0, acc0);
        acc1 += a1; acc1 = fmaf(tt, b1 - a1, acc1);
    }

    out[b * DIM_J + jp]     = acc0;
    out[b * DIM_J + jp + 1] = acc1;
}

extern "C" void kernel_launch(void* const* d_in, const int* in_sizes, int n_in,
                              void* d_out, int out_size, void* d_ws, size_t ws_size,
                              hipStream_t stream) {
    const float* x  = (const float*)d_in[0];
    const float* Xg = (const float*)d_in[1];
    const float* Y  = (const float*)d_in[2];
    float* out = (float*)d_out;
    unsigned short* Y2 = (unsigned short*)d_ws;  // 8.4 MB bf16 scratch

    kan_transpose<<<B_N, 256, 0, stream>>>(Y, Y2);
    kan_main<<<B_N, 128, 0, stream>>>(x, Xg, Y2, out);
}